// Round 15
// baseline (994.901 us; speedup 1.0000x reference)
//
#include <hip/hip_runtime.h>
#include <hip/hip_bf16.h>
#include <math.h>

#define NN 100000
#define NE_TOT 600000
#define NG 2000
#define HD 128
#define NL 3
#define LN_EPS 1e-5f

typedef __attribute__((ext_vector_type(8))) short short8;   // 8 bf16 (4 VGPR)
typedef __attribute__((ext_vector_type(4))) float f32x4;

// HW-rounding casts (RNE) — compiler pattern-matches to v_cvt_pk_bf16_f32.
__device__ __forceinline__ unsigned short f2bf(float f){
  union { __hip_bfloat16 h; unsigned short u; } x;
  x.h = __float2bfloat16(f);
  return x.u;
}
__device__ __forceinline__ unsigned int pack_bf16x2(float lo, float hi){
  union { __hip_bfloat162 h; unsigned int u; } x;
  x.h = __float22bfloat162_rn(make_float2(lo, hi));
  return x.u;
}
// Manual 3-op RNE cast — used in k_gru (shortest live ranges).
__device__ __forceinline__ unsigned short f2bf_m(float f){
  union { float f; unsigned int u; } x; x.f = f;
  unsigned int r = (x.u + 0x7FFFu + ((x.u >> 16) & 1u)) >> 16;
  return (unsigned short)r;
}
__device__ __forceinline__ float bf2f(unsigned short u){
  union { unsigned int i; float f; } x; x.i = ((unsigned int)u) << 16; return x.f;
}
__device__ __forceinline__ float asfloat_u(unsigned int u){
  union { unsigned int i; float f; } x; x.i = u; return x.f;
}

__device__ __forceinline__ float wave_sum64(float v){
  #pragma unroll
  for (int o = 32; o > 0; o >>= 1) v += __shfl_xor(v, o, 64);
  return v;
}

// ---------------- zero-fill (cnt) ----------------
__global__ __launch_bounds__(256) void k_zero4(float4* p, int n4){
  int i = blockIdx.x * 256 + threadIdx.x;
  if (i < n4) p[i] = make_float4(0.f, 0.f, 0.f, 0.f);
}

// ---------------- CSR build: histogram / hierarchical scan / scatter ----------------
__global__ __launch_bounds__(256) void k_hist(const int* __restrict__ ei, int* __restrict__ cnt){
  int e = blockIdx.x * 256 + threadIdx.x;
  if (e < NE_TOT) atomicAdd(&cnt[ei[NE_TOT + e]], 1);
}

__global__ __launch_bounds__(1024) void k_scan1(const int* __restrict__ cnt,
                                                int* __restrict__ loc,
                                                int* __restrict__ bsum){
  __shared__ int w_s[16];
  int t = threadIdx.x, lane = t & 63, wv = t >> 6;
  int g = blockIdx.x * 1024 + t;
  int v = (g < NN) ? cnt[g] : 0;
  int s = v;
  #pragma unroll
  for (int o = 1; o < 64; o <<= 1){
    int u = __shfl_up(s, o, 64);
    if (lane >= o) s += u;
  }
  if (lane == 63) w_s[wv] = s;
  __syncthreads();
  if (t == 0){
    int run = 0;
    #pragma unroll
    for (int i = 0; i < 16; ++i){ int c = w_s[i]; w_s[i] = run; run += c; }
    bsum[blockIdx.x] = run;
  }
  __syncthreads();
  if (g < NN) loc[g] = s - v + w_s[wv];   // exclusive within block
}

__global__ __launch_bounds__(128) void k_scan2(const int* __restrict__ bsum,
                                               int* __restrict__ bscan){
  __shared__ int w0_s;
  int t = threadIdx.x, lane = t & 63, wv = t >> 6;
  int v = (t < 98) ? bsum[t] : 0;
  int s = v;
  #pragma unroll
  for (int o = 1; o < 64; o <<= 1){
    int u = __shfl_up(s, o, 64);
    if (lane >= o) s += u;
  }
  if (wv == 0 && lane == 63) w0_s = s;
  __syncthreads();
  if (wv == 1) s += w0_s;
  if (t < 98) bscan[t] = s - v;           // exclusive
}

__global__ __launch_bounds__(1024) void k_scan3(const int* __restrict__ loc,
                                                const int* __restrict__ bscan,
                                                int* __restrict__ cur){
  int g = blockIdx.x * 1024 + threadIdx.x;
  if (g < NN) cur[g] = loc[g] + bscan[blockIdx.x];
}

__global__ __launch_bounds__(256) void k_scatter(const int* __restrict__ ei,
    const float* __restrict__ eattr, int* __restrict__ cur,
    int* __restrict__ srcs, int* __restrict__ dsts, float* __restrict__ attrs){
  int e = blockIdx.x * 256 + threadIdx.x;
  if (e >= NE_TOT) return;
  int d = ei[NE_TOT + e];
  int p = atomicAdd(&cur[d], 1);
  srcs[p] = ei[e];
  dsts[p] = d;
  attrs[p] = eattr[e];
}

// ------------- prep GRU weights -> bf16 MFMA-B layout -------------
#define GW_LPL 102400
#define GW_O2  67584
#define GW_O3  84992
__global__ __launch_bounds__(256) void k_gprep(const float* __restrict__ wih,
                                               const float* __restrict__ whh,
                                               unsigned short* __restrict__ gw){
  int idx = blockIdx.x * 256 + threadIdx.x;
  if (idx >= 2 * 3 * 384 * 128) return;
  int which = (idx >= 3 * 384 * 128);
  int i = which ? idx - 3 * 384 * 128 : idx;
  int l = i / 49152;
  int r = i - l * 49152;
  int j = r >> 7, k = r & 127;
  float v = which ? whh[i] : wih[i];
  size_t o;
  if (!which){
    o = (j < 256) ? ((size_t)l * GW_LPL + (size_t)j * 264 + k)
                  : ((size_t)l * GW_LPL + GW_O2 + (size_t)(j - 256) * 136 + k);
  } else {
    o = (j < 256) ? ((size_t)l * GW_LPL + (size_t)j * 264 + 128 + k)
                  : ((size_t)l * GW_LPL + GW_O3 + (size_t)(j - 256) * 136 + k);
  }
  gw[o] = f2bf(v);
}

// ------------- prep message W1 -> node-GEMM layout [3][512 j][136 k] -------------
#define W1N_LS (512 * 136)
__global__ __launch_bounds__(256) void k_mprep(const float* __restrict__ w1,
                                               unsigned short* __restrict__ w1n){
  int idx = blockIdx.x * 256 + threadIdx.x;
  if (idx >= 3 * 512 * 128) return;
  int l = idx / (512 * 128);
  int r = idx - l * (512 * 128);
  int j = r >> 7, k = r & 127;
  const float* wl = w1 + (size_t)l * 257 * 256;
  float v = (j < 256) ? wl[k * 256 + j] : wl[(128 + k) * 256 + (j - 256)];
  w1n[(size_t)l * W1N_LS + j * 136 + k] = f2bf(v);
}

// ------------- prep message W2 -> [3][128 col][264 k] -------------
#define W2T_LS (128 * 264)
__global__ __launch_bounds__(256) void k_w2prep(const float* __restrict__ w2,
                                                unsigned short* __restrict__ w2T){
  int idx = blockIdx.x * 256 + threadIdx.x;
  if (idx >= 3 * 128 * 256) return;
  int l = idx >> 15;
  int r = idx & 32767;
  int c = r >> 8, k = r & 255;
  w2T[(size_t)l * W2T_LS + c * 264 + k] = f2bf(w2[(size_t)l * 256 * 128 + k * 128 + c]);
}

// ---------------- encoder: xbf = LN(relu(af @ enc_w + b)) ----------------
__global__ __launch_bounds__(256) void k_enc(const float* __restrict__ af,
    const float* __restrict__ w, const float* __restrict__ b,
    const float* __restrict__ lg, const float* __restrict__ lb,
    unsigned short* __restrict__ xbf){
  int wv = threadIdx.x >> 6, lane = threadIdx.x & 63;
  int n = blockIdx.x * 4 + wv;
  float4 a = *reinterpret_cast<const float4*>(af + (size_t)n * 4);
  int c0 = lane, c1 = lane + 64;
  float v0 = fmaf(a.x, w[c0], fmaf(a.y, w[128 + c0], fmaf(a.z, w[256 + c0], fmaf(a.w, w[384 + c0], b[c0]))));
  float v1 = fmaf(a.x, w[c1], fmaf(a.y, w[128 + c1], fmaf(a.z, w[256 + c1], fmaf(a.w, w[384 + c1], b[c1]))));
  v0 = fmaxf(v0, 0.f); v1 = fmaxf(v1, 0.f);
  float m = wave_sum64(v0 + v1) * (1.f / 128.f);
  float d0 = v0 - m, d1 = v1 - m;
  float var = wave_sum64(d0 * d0 + d1 * d1) * (1.f / 128.f);
  float rstd = rsqrtf(var + LN_EPS);
  xbf[(size_t)n * HD + c0] = f2bf(d0 * rstd * lg[c0] + lb[c0]);
  xbf[(size_t)n * HD + c1] = f2bf(d1 * rstd * lg[c1] + lb[c1]);
}

// ---------------- node GEMM: gsd[n][512] = [x@w1_top | x@w1_mid + b1] ----------------
// 2 col-half blocks (cg = blockIdx&1): block = 64 nodes x 256 cols,
// wave = 32 nodes x 128 cols, acc[2][8] = 64 VGPR -> 3+ waves/SIMD occupancy.
// cg==0 blocks also init aggr rows to indeg[n]*b2[c].
__global__ __launch_bounds__(256, 3) void k_ngemm(const unsigned short* __restrict__ xbf,
    const unsigned short* __restrict__ w1n, const float* __restrict__ b1,
    unsigned short* __restrict__ gsd, float* __restrict__ aggr,
    const int* __restrict__ cnt, const float* __restrict__ b2){
  int tid = threadIdx.x, lane = tid & 63, wv = tid >> 6;
  int r16 = lane & 15, kg = lane >> 4;
  int nb = blockIdx.x >> 1, cg = blockIdx.x & 1;
  int rg = wv >> 1, sg = wv & 1;
  // aggr init: aggr[n][c] = indeg[n] * b2[c]  (cg==0 blocks only)
  if (cg == 0){
    int nrow = NN - nb * 64; if (nrow > 64) nrow = 64;
    for (int i = tid; i < nrow * 32; i += 256){
      int row = i >> 5, c4 = (i & 31) * 4;
      int n = nb * 64 + row;
      float cv = (float)cnt[n];
      float4 bb = *reinterpret_cast<const float4*>(b2 + c4);
      bb.x *= cv; bb.y *= cv; bb.z *= cv; bb.w *= cv;
      *reinterpret_cast<float4*>(aggr + (size_t)n * HD + c4) = bb;
    }
  }
  int n0 = nb * 64 + rg * 32 + r16;
  int n1 = n0 + 16;
  int nc0 = (n0 < NN) ? n0 : NN - 1;
  int nc1 = (n1 < NN) ? n1 : NN - 1;
  short8 bfr[2][4];
  #pragma unroll
  for (int k0 = 0; k0 < 4; ++k0){
    bfr[0][k0] = *reinterpret_cast<const short8*>(xbf + (size_t)nc0 * HD + k0 * 32 + kg * 8);
    bfr[1][k0] = *reinterpret_cast<const short8*>(xbf + (size_t)nc1 * HD + k0 * 32 + kg * 8);
  }
  f32x4 acc[2][8];
  #pragma unroll
  for (int nt = 0; nt < 2; ++nt)
    #pragma unroll
    for (int it = 0; it < 8; ++it) acc[nt][it] = (f32x4){0.f, 0.f, 0.f, 0.f};
  #pragma unroll
  for (int it = 0; it < 8; ++it){
    const unsigned short* ap = w1n + (size_t)(cg * 256 + sg * 128 + it * 16 + r16) * 136 + kg * 8;
    #pragma unroll
    for (int k0 = 0; k0 < 4; ++k0){
      short8 af = *reinterpret_cast<const short8*>(ap + k0 * 32);
      acc[0][it] = __builtin_amdgcn_mfma_f32_16x16x32_bf16(af, bfr[0][k0], acc[0][it], 0, 0, 0);
      acc[1][it] = __builtin_amdgcn_mfma_f32_16x16x32_bf16(af, bfr[1][k0], acc[1][it], 0, 0, 0);
    }
  }
  #pragma unroll
  for (int nt = 0; nt < 2; ++nt){
    int n = nb * 64 + rg * 32 + nt * 16 + r16;
    if (n < NN){
      #pragma unroll
      for (int it = 0; it < 8; ++it){
        int co = sg * 128 + it * 16 + kg * 4;     // col within this cg's 256
        float v0 = acc[nt][it][0], v1 = acc[nt][it][1], v2 = acc[nt][it][2], v3 = acc[nt][it][3];
        if (cg){            // gd half: + b1
          v0 += b1[co]; v1 += b1[co + 1]; v2 += b1[co + 2]; v3 += b1[co + 3];
        }
        uint2 hp;
        hp.x = pack_bf16x2(v0, v1);
        hp.y = pack_bf16x2(v2, v3);
        *reinterpret_cast<uint2*>(gsd + (size_t)n * 512 + cg * 256 + co) = hp;
      }
    }
  }
}

// ---------------- message kernel: gather+relu -> GEMM2 -> segmented reduce ----------------
// R11 structure (EBM=64, LDS h_s, 4-rt-tile GEMM2 for 4x B-reuse); phase-1 pair-unpack
// + cvt_pk pack; b2 bias folded into aggr init (k_ngemm).
#define EBM 64
__global__ __launch_bounds__(256, 4) void k_msg(const unsigned short* __restrict__ gsd,
    const int* __restrict__ srcs, const int* __restrict__ dsts,
    const float* __restrict__ attrs, const float* __restrict__ w1attr,
    const unsigned short* __restrict__ w2T,
    float* __restrict__ aggr){
  __shared__ __align__(16) unsigned char smem[33280];   // h_s (32KB) / scratch f32 (33.3KB)
  unsigned short* h_s = (unsigned short*)smem;
  float* scr = (float*)smem;
  __shared__ float w1a_s[256];
  __shared__ int   dst_s[EBM];
  __shared__ float attr_s[EBM];
  int tid = threadIdx.x;
  int lane = tid & 63, wv = tid >> 6;
  int r16 = lane & 15, kg = lane >> 4;
  int ebase = blockIdx.x * EBM;

  w1a_s[tid] = w1attr[tid & 255];
  if (tid < EBM){ dst_s[tid] = dsts[ebase + tid]; attr_s[tid] = attrs[ebase + tid]; }
  __syncthreads();

  // phase 1: hidden = relu(gs[src] + gd[dst] + attr*w1attr) -> h_s bf16 (swizzled)
  {
    int e = tid >> 2, q = tid & 3;
    int sn = srcs[ebase + e];
    int dn = dst_s[e];
    float at = attr_s[e];
    const uint4* gp = reinterpret_cast<const uint4*>(gsd + (size_t)sn * 512);
    const uint4* dp = reinterpret_cast<const uint4*>(gsd + (size_t)dn * 512 + 256);
    uint4 gv[8], dv[8];
    #pragma unroll
    for (int j8 = 0; j8 < 8; ++j8){
      gv[j8] = gp[j8 * 4 + q];
      dv[j8] = dp[j8 * 4 + q];
    }
    __builtin_amdgcn_sched_barrier(0);
    #pragma unroll
    for (int j8 = 0; j8 < 8; ++j8){
      int colb = j8 * 32 + q * 8;
      unsigned int hh[4];
      unsigned int ug[4] = {gv[j8].x, gv[j8].y, gv[j8].z, gv[j8].w};
      unsigned int ud[4] = {dv[j8].x, dv[j8].y, dv[j8].z, dv[j8].w};
      #pragma unroll
      for (int w = 0; w < 4; ++w){
        float glo = asfloat_u(ug[w] << 16), ghi = asfloat_u(ug[w] & 0xFFFF0000u);
        float dlo = asfloat_u(ud[w] << 16), dhi = asfloat_u(ud[w] & 0xFFFF0000u);
        float vlo = fmaxf(glo + dlo + at * w1a_s[colb + 2 * w],     0.f);
        float vhi = fmaxf(ghi + dhi + at * w1a_s[colb + 2 * w + 1], 0.f);
        hh[w] = pack_bf16x2(vlo, vhi);
      }
      int slot = colb >> 3;
      int slotw = (slot & ~7) | ((slot ^ e) & 7);
      *reinterpret_cast<uint4*>(&h_s[e * 256 + slotw * 8]) =
          make_uint4(hh[0], hh[1], hh[2], hh[3]);
    }
  }
  __syncthreads();

  // phase 2: GEMM2 [64,256] @ [256,128] (4 row-tiles x 2 col-tiles per wave: 4x B-reuse)
  f32x4 acc2[4][2];
  #pragma unroll
  for (int rt = 0; rt < 4; ++rt)
    #pragma unroll
    for (int ct = 0; ct < 2; ++ct)
      acc2[rt][ct] = (f32x4){0.f, 0.f, 0.f, 0.f};
  int cbase2 = wv * 32;
  {
    short8 a[4], bb[2];
    const unsigned short* w2b = w2T + (size_t)(cbase2 + r16) * 264 + kg * 8;
    for (int k0 = 0; k0 < 8; ++k0){
      #pragma unroll
      for (int rt = 0; rt < 4; ++rt){
        int row = rt * 16 + r16;
        int slot = k0 * 4 + kg;
        int slotw = (slot & ~7) | ((slot ^ row) & 7);
        a[rt] = *reinterpret_cast<const short8*>(&h_s[row * 256 + slotw * 8]);
      }
      #pragma unroll
      for (int ct = 0; ct < 2; ++ct)
        bb[ct] = *reinterpret_cast<const short8*>(w2b + ct * 16 * 264 + k0 * 32);
      #pragma unroll
      for (int rt = 0; rt < 4; ++rt)
        #pragma unroll
        for (int ct = 0; ct < 2; ++ct)
          acc2[rt][ct] = __builtin_amdgcn_mfma_f32_16x16x32_bf16(a[rt], bb[ct], acc2[rt][ct], 0, 0, 0);
    }
  }
  __syncthreads();   // all h_s reads done; smem becomes scratch

  // phase 3: write messages f32 to scratch (stride 130 words: conflict-free)
  #pragma unroll
  for (int ct = 0; ct < 2; ++ct){
    int col = cbase2 + ct * 16 + r16;
    #pragma unroll
    for (int rt = 0; rt < 4; ++rt){
      #pragma unroll
      for (int r = 0; r < 4; ++r){
        int row = rt * 16 + kg * 4 + r;
        scr[row * 130 + col] = acc2[rt][ct][r];
      }
    }
  }
  __syncthreads();

  // phase 4: segmented reduce over sorted dst + atomic flush (bias pre-folded into aggr)
  {
    int c = tid & 127, h = tid >> 7;
    int r0 = h * 32;
    int pd = dst_s[r0];
    float acc = scr[r0 * 130 + c];
    #pragma unroll 4
    for (int r = 1; r < 32; ++r){
      int row = r0 + r;
      float v = scr[row * 130 + c];
      int d = dst_s[row];
      if (d != pd){
        atomicAdd(&aggr[(size_t)pd * HD + c], acc);
        acc = v; pd = d;
      } else {
        acc += v;
      }
    }
    atomicAdd(&aggr[(size_t)pd * HD + c], acc);
  }
}

// ---------------- MFMA GRUCell + residual + LayerNorm (in-place on xbf) ----------------
// 4 waves = 2 row-groups x 2 col-groups; wave = 32 rows x 64 j-cols.
// Plain launch_bounds(256): let the allocator take ~180 VGPR with zero spill
// (the (256,2) cap forced ~48MB of scratch traffic — R14 counters).
#define GRB 64
__global__ __launch_bounds__(256) void k_gru(unsigned short* __restrict__ xbf,
    const float* __restrict__ aggr,
    const unsigned short* __restrict__ gw,
    const float* __restrict__ bih, const float* __restrict__ bhh,
    const float* __restrict__ lg, const float* __restrict__ lb){
  __shared__ unsigned short a_s[GRB * 256];
  __shared__ float psum[GRB][2][2];
  int tid = threadIdx.x;
  int lane = tid & 63, wv = tid >> 6;
  int r16 = lane & 15, kg = lane >> 4;
  int rg = wv >> 1, cg = wv & 1;
  int nbase = blockIdx.x * GRB;

  // gather aggr (f32->bf16, manual cast): rows 64 x k 0..127
  {
    int row = tid >> 2, qc = (tid & 3) * 32;
    int n = nbase + row; if (n >= NN) n = NN - 1;
    const float* ap = aggr + (size_t)n * HD + qc;
    #pragma unroll
    for (int j = 0; j < 8; ++j){
      float4 v = *reinterpret_cast<const float4*>(ap + j * 4);
      ushort4 h;
      h.x = f2bf_m(v.x); h.y = f2bf_m(v.y); h.z = f2bf_m(v.z); h.w = f2bf_m(v.w);
      int col = qc + j * 4;
      int slot = col >> 3;
      int slotw = (slot & ~7) | ((slot ^ row) & 7);
      *reinterpret_cast<ushort4*>(&a_s[row * 256 + slotw * 8 + (col & 7)]) = h;
    }
  }
  // gather x (bf16): rows 64 x k 128..255
  {
    int row = tid >> 2, q = tid & 3;
    int n = nbase + row; if (n >= NN) n = NN - 1;
    const unsigned short* xp = xbf + (size_t)n * HD + q * 32;
    #pragma unroll
    for (int j = 0; j < 4; ++j){
      int4 v = *reinterpret_cast<const int4*>(xp + j * 8);
      int col = 128 + q * 32 + j * 8;
      int slot = col >> 3;
      int slotw = (slot & ~7) | ((slot ^ row) & 7);
      *reinterpret_cast<int4*>(&a_s[row * 256 + slotw * 8]) = v;
    }
  }
  __syncthreads();

  // A-fragments: 2 row-tiles x 8 K-steps
  short8 a[2][8];
  #pragma unroll
  for (int rt = 0; rt < 2; ++rt){
    int arow = rg * 32 + rt * 16 + r16;
    #pragma unroll
    for (int k0 = 0; k0 < 8; ++k0){
      int slot = k0 * 4 + kg;
      int slotw = (slot & ~7) | ((slot ^ arow) & 7);
      a[rt][k0] = *reinterpret_cast<const short8*>(&a_s[arow * 256 + slotw * 8]);
    }
  }

  f32x4 accR[2][4], accZ[2][4], accI[2][4], accH[2][4];
  #pragma unroll
  for (int rt = 0; rt < 2; ++rt)
    #pragma unroll
    for (int ct = 0; ct < 4; ++ct){
      accR[rt][ct] = (f32x4){0.f, 0.f, 0.f, 0.f};
      accZ[rt][ct] = (f32x4){0.f, 0.f, 0.f, 0.f};
      accI[rt][ct] = (f32x4){0.f, 0.f, 0.f, 0.f};
      accH[rt][ct] = (f32x4){0.f, 0.f, 0.f, 0.f};
    }

  int jb = cg * 64;
  #pragma unroll
  for (int ct = 0; ct < 4; ++ct){
    const unsigned short* bpR = gw + (size_t)(jb + ct * 16 + r16) * 264 + kg * 8;
    const unsigned short* bpZ = gw + (size_t)(128 + jb + ct * 16 + r16) * 264 + kg * 8;
    #pragma unroll
    for (int k0 = 0; k0 < 8; ++k0){
      short8 bR = *reinterpret_cast<const short8*>(bpR + k0 * 32);
      accR[0][ct] = __builtin_amdgcn_mfma_f32_16x16x32_bf16(a[0][k0], bR, accR[0][ct], 0, 0, 0);
      accR[1][ct] = __builtin_amdgcn_mfma_f32_16x16x32_bf16(a[1][k0], bR, accR[1][ct], 0, 0, 0);
      short8 bZ = *reinterpret_cast<const short8*>(bpZ + k0 * 32);
      accZ[0][ct] = __builtin_amdgcn_mfma_f32_16x16x32_bf16(a[0][k0], bZ, accZ[0][ct], 0, 0, 0);
      accZ[1][ct] = __builtin_amdgcn_mfma_f32_16x16x32_bf16(a[1][k0], bZ, accZ[1][ct], 0, 0, 0);
    }
    const unsigned short* bpI = gw + GW_O2 + (size_t)(jb + ct * 16 + r16) * 136 + kg * 8;
    const unsigned short* bpH = gw + GW_O3 + (size_t)(jb + ct * 16 + r16) * 136 + kg * 8;
    #pragma unroll
    for (int k0 = 0; k0 < 4; ++k0){
      short8 bI = *reinterpret_cast<const short8*>(bpI + k0 * 32);
      accI[0][ct] = __builtin_amdgcn_mfma_f32_16x16x32_bf16(a[0][k0], bI, accI[0][ct], 0, 0, 0);
      accI[1][ct] = __builtin_amdgcn_mfma_f32_16x16x32_bf16(a[1][k0], bI, accI[1][ct], 0, 0, 0);
      short8 bH = *reinterpret_cast<const short8*>(bpH + k0 * 32);
      accH[0][ct] = __builtin_amdgcn_mfma_f32_16x16x32_bf16(a[0][k0 + 4], bH, accH[0][ct], 0, 0, 0);
      accH[1][ct] = __builtin_amdgcn_mfma_f32_16x16x32_bf16(a[1][k0 + 4], bH, accH[1][ct], 0, 0, 0);
    }
  }

  // gates + residual; pre-LN value overwrites accR (fast tanh: 2*sigma(2x)-1).
  // Residual x read from LDS a_s (cols 128..255) — no global xbf re-read.
  #pragma unroll
  for (int rt = 0; rt < 2; ++rt){
    #pragma unroll
    for (int ct = 0; ct < 4; ++ct){
      int j = jb + ct * 16 + r16;
      float br = bih[j] + bhh[j];
      float bz = bih[j + 128] + bhh[j + 128];
      float bin = bih[j + 256], bhn = bhh[j + 256];
      #pragma unroll
      for (int r = 0; r < 4; ++r){
        int row = rg * 32 + rt * 16 + kg * 4 + r;
        int col = 128 + j;
        int slot = col >> 3;
        int slotw = (slot & ~7) | ((slot ^ row) & 7);
        float xv = bf2f(a_s[row * 256 + slotw * 8 + (col & 7)]);
        float rgt = accR[rt][ct][r] + br;  rgt = 1.f / (1.f + __expf(-rgt));
        float zg  = accZ[rt][ct][r] + bz;  zg  = 1.f / (1.f + __expf(-zg));
        float na  = accI[rt][ct][r] + bin + rgt * (accH[rt][ct][r] + bhn);
        float sg  = 1.f / (1.f + __expf(-2.f * na));
        float ng  = fmaf(2.f, sg, -1.f);
        accR[rt][ct][r] = xv + (1.f - zg) * ng + zg * xv;   // pre-LN
      }
    }
  }

  // cross-wave LN: per-row partial (sum, sumsq) via 16-lane shfl -> LDS psum[row][cg]
  #pragma unroll
  for (int rt = 0; rt < 2; ++rt){
    #pragma unroll
    for (int r = 0; r < 4; ++r){
      float s = 0.f, q = 0.f;
      #pragma unroll
      for (int ct = 0; ct < 4; ++ct){ float v = accR[rt][ct][r]; s += v; q += v * v; }
      #pragma unroll
      for (int o = 1; o <= 8; o <<= 1){ s += __shfl_xor(s, o, 64); q += __shfl_xor(q, o, 64); }
      if (r16 == 0){
        int l = rg * 32 + rt * 16 + kg * 4 + r;
        psum[l][cg][0] = s;
        psum[l][cg][1] = q;
      }
    }
  }
  __syncthreads();

  #pragma unroll
  for (int rt = 0; rt < 2; ++rt){
    #pragma unroll
    for (int r = 0; r < 4; ++r){
      int l = rg * 32 + rt * 16 + kg * 4 + r;
      float S = psum[l][0][0] + psum[l][1][0];
      float Q = psum[l][0][1] + psum[l][1][1];
      float m = S * (1.f / 128.f);
      float var = Q * (1.f / 128.f) - m * m;
      float rstd = rsqrtf(fmaxf(var, 0.f) + LN_EPS);
      int n = nbase + rg * 32 + rt * 16 + kg * 4 + r;
      if (n < NN){
        #pragma unroll
        for (int ct = 0; ct < 4; ++ct){
          int j = jb + ct * 16 + r16;
          xbf[(size_t)n * HD + j] = f2bf_m((accR[rt][ct][r] - m) * rstd * lg[j] + lb[j]);
        }
      }
    }
  }
}

// ---------------- pooling + readout MLP ----------------
__device__ __forceinline__ int lowerb(const int* __restrict__ a, int v){
  int lo = 0, hi = NN;
  while (lo < hi){ int mid = (lo + hi) >> 1; if (a[mid] < v) lo = mid + 1; else hi = mid; }
  return lo;
}

__global__ __launch_bounds__(128) void k_pool(const unsigned short* __restrict__ xbf,
    const int* __restrict__ batch,
    const float* __restrict__ w1, const float* __restrict__ b1,
    const float* __restrict__ w2, const float* __restrict__ b2,
    const float* __restrict__ w3, const float* __restrict__ b3,
    float* __restrict__ out){
  __shared__ float g_s[256];
  __shared__ float h1_s[128];
  __shared__ float h2_s[64];
  int g = blockIdx.x, tid = threadIdx.x;
  int s = lowerb(batch, g), t = lowerb(batch, g + 1);
  float sum = 0.f, mx = -INFINITY;
  for (int n = s; n < t; ++n){
    float v = bf2f(xbf[(size_t)n * HD + tid]);
    sum += v; mx = fmaxf(mx, v);
  }
  int cnt = t - s;
  g_s[tid]       = sum / fmaxf((float)cnt, 1.f);
  g_s[tid + 128] = (cnt > 0) ? mx : -INFINITY;
  __syncthreads();
  float a1 = b1[tid];
  for (int k = 0; k < 256; ++k) a1 = fmaf(g_s[k], w1[k * 128 + tid], a1);
  h1_s[tid] = fmaxf(a1, 0.f);
  __syncthreads();
  if (tid < 64){
    float a2 = b2[tid];
    for (int k = 0; k < 128; ++k) a2 = fmaf(h1_s[k], w2[k * 64 + tid], a2);
    h2_s[tid] = fmaxf(a2, 0.f);
  }
  __syncthreads();
  if (tid < 113){
    float a3 = b3[tid];
    for (int k = 0; k < 64; ++k) a3 = fmaf(h2_s[k], w3[k * 113 + tid], a3);
    out[(size_t)g * 113 + tid] = a3;
  }
}

// ---------------- launcher ----------------
extern "C" void kernel_launch(void* const* d_in, const int* in_sizes, int n_in,
                              void* d_out, int out_size, void* d_ws, size_t ws_size,
                              hipStream_t stream){
  (void)in_sizes; (void)n_in; (void)out_size; (void)ws_size;
  const float* af     = (const float*)d_in[0];
  const int*   ei     = (const int*)  d_in[1];
  const float* eattr  = (const float*)d_in[2];
  const int*   batch  = (const int*)  d_in[3];
  const float* enc_w  = (const float*)d_in[4];
  const float* enc_b  = (const float*)d_in[5];
  const float* enc_lg = (const float*)d_in[6];
  const float* enc_lb = (const float*)d_in[7];
  const float* mw1    = (const float*)d_in[8];
  const float* mb1    = (const float*)d_in[9];
  const float* mw2    = (const float*)d_in[10];
  const float* mb2    = (const float*)d_in[11];
  const float* gwih   = (const float*)d_in[12];
  const float* gwhh   = (const float*)d_in[13];
  const float* gbih   = (const float*)d_in[14];
  const float* gbhh   = (const float*)d_in[15];
  const float* lng    = (const float*)d_in[16];
  const float* lnb    = (const float*)d_in[17];
  const float* rw1    = (const float*)d_in[18];
  const float* rb1    = (const float*)d_in[19];
  const float* rw2    = (const float*)d_in[20];
  const float* rb2    = (const float*)d_in[21];
  const float* rw3    = (const float*)d_in[22];
  const float* rb3    = (const float*)d_in[23];
  float* out = (float*)d_out;
  char* ws = (char*)d_ws;

  size_t off = 0;
  auto carve = [&](size_t bytes)->char*{
    char* p = ws + off;
    off = (off + bytes + 255) & ~(size_t)255;
    return p;
  };
  unsigned short* xbf  = (unsigned short*)carve((size_t)NN * HD * 2);       // 25.6 MB
  float*          aggr = (float*)         carve((size_t)NN * HD * 4);       // 51.2 MB
  unsigned short* gsd  = (unsigned short*)carve((size_t)NN * 512 * 2);      // 102.4 MB
  unsigned short* gw   = (unsigned short*)carve((size_t)3 * GW_LPL * 2);
  unsigned short* w1n  = (unsigned short*)carve((size_t)3 * W1N_LS * 2);
  unsigned short* w2T  = (unsigned short*)carve((size_t)3 * W2T_LS * 2);
  int*   cnt   = (int*)  carve((size_t)NN * 4);
  int*   cur   = (int*)  carve((size_t)NN * 4);
  int*   loc   = (int*)  carve((size_t)NN * 4);
  int*   bsum  = (int*)  carve((size_t)128 * 4);
  int*   bscan = (int*)  carve((size_t)128 * 4);
  int*   srcs  = (int*)  carve((size_t)NE_TOT * 4);
  int*   dsts  = (int*)  carve((size_t)NE_TOT * 4);
  float* attrs = (float*)carve((size_t)NE_TOT * 4);

  // one-time: CSR sort + weight preps + encoder
  k_zero4<<<(NN / 4 + 255) / 256, 256, 0, stream>>>((float4*)cnt, NN / 4);
  k_hist<<<(NE_TOT + 255) / 256, 256, 0, stream>>>(ei, cnt);
  k_scan1<<<98, 1024, 0, stream>>>(cnt, loc, bsum);
  k_scan2<<<1, 128, 0, stream>>>(bsum, bscan);
  k_scan3<<<98, 1024, 0, stream>>>(loc, bscan, cur);
  k_scatter<<<(NE_TOT + 255) / 256, 256, 0, stream>>>(ei, eattr, cur, srcs, dsts, attrs);
  k_gprep<<<1152, 256, 0, stream>>>(gwih, gwhh, gw);
  k_mprep<<<768, 256, 0, stream>>>(mw1, w1n);
  k_w2prep<<<384, 256, 0, stream>>>(mw2, w2T);
  k_enc<<<NN / 4, 256, 0, stream>>>(af, enc_w, enc_b, enc_lg, enc_lb, xbf);

  for (int l = 0; l < NL; ++l){
    k_ngemm<<<2 * ((NN + 63) / 64), 256, 0, stream>>>(xbf,
        w1n + (size_t)l * W1N_LS, mb1 + (size_t)l * 256, gsd, aggr,
        cnt, mb2 + (size_t)l * 128);
    k_msg<<<NE_TOT / EBM, 256, 0, stream>>>(gsd, srcs, dsts, attrs,
        mw1 + (size_t)l * 257 * 256 + 256 * 256,
        w2T + (size_t)l * W2T_LS, aggr);
    k_gru<<<(NN + GRB - 1) / GRB, 256, 0, stream>>>(xbf, aggr,
        gw + (size_t)l * GW_LPL,
        gbih + (size_t)l * 384, gbhh + (size_t)l * 384,
        lng + (size_t)l * HD, lnb + (size_t)l * HD);
  }
  k_pool<<<NG, 128, 0, stream>>>(xbf, batch, rw1, rb1, rw2, rb2, rw3, rb3, out);
}

// Round 16
// 922.229 us; speedup vs baseline: 1.0788x; 1.0788x over previous
//
#include <hip/hip_runtime.h>
#include <hip/hip_bf16.h>
#include <math.h>

#define NN 100000
#define NE_TOT 600000
#define NG 2000
#define HD 128
#define NL 3
#define LN_EPS 1e-5f

typedef __attribute__((ext_vector_type(8))) short short8;   // 8 bf16 (4 VGPR)
typedef __attribute__((ext_vector_type(4))) float f32x4;

// HW-rounding casts (RNE) — compiler pattern-matches to v_cvt_pk_bf16_f32.
__device__ __forceinline__ unsigned short f2bf(float f){
  union { __hip_bfloat16 h; unsigned short u; } x;
  x.h = __float2bfloat16(f);
  return x.u;
}
__device__ __forceinline__ unsigned int pack_bf16x2(float lo, float hi){
  union { __hip_bfloat162 h; unsigned int u; } x;
  x.h = __float22bfloat162_rn(make_float2(lo, hi));
  return x.u;
}
// Manual 3-op RNE cast — used in k_gru (register-pressure-critical).
__device__ __forceinline__ unsigned short f2bf_m(float f){
  union { float f; unsigned int u; } x; x.f = f;
  unsigned int r = (x.u + 0x7FFFu + ((x.u >> 16) & 1u)) >> 16;
  return (unsigned short)r;
}
__device__ __forceinline__ float bf2f(unsigned short u){
  union { unsigned int i; float f; } x; x.i = ((unsigned int)u) << 16; return x.f;
}
__device__ __forceinline__ float asfloat_u(unsigned int u){
  union { unsigned int i; float f; } x; x.i = u; return x.f;
}

__device__ __forceinline__ float wave_sum64(float v){
  #pragma unroll
  for (int o = 32; o > 0; o >>= 1) v += __shfl_xor(v, o, 64);
  return v;
}

// ---------------- zero-fill (cnt) ----------------
__global__ __launch_bounds__(256) void k_zero4(float4* p, int n4){
  int i = blockIdx.x * 256 + threadIdx.x;
  if (i < n4) p[i] = make_float4(0.f, 0.f, 0.f, 0.f);
}

// ---------------- CSR build: histogram / hierarchical scan / scatter ----------------
__global__ __launch_bounds__(256) void k_hist(const int* __restrict__ ei, int* __restrict__ cnt){
  int e = blockIdx.x * 256 + threadIdx.x;
  if (e < NE_TOT) atomicAdd(&cnt[ei[NE_TOT + e]], 1);
}

__global__ __launch_bounds__(1024) void k_scan1(const int* __restrict__ cnt,
                                                int* __restrict__ loc,
                                                int* __restrict__ bsum){
  __shared__ int w_s[16];
  int t = threadIdx.x, lane = t & 63, wv = t >> 6;
  int g = blockIdx.x * 1024 + t;
  int v = (g < NN) ? cnt[g] : 0;
  int s = v;
  #pragma unroll
  for (int o = 1; o < 64; o <<= 1){
    int u = __shfl_up(s, o, 64);
    if (lane >= o) s += u;
  }
  if (lane == 63) w_s[wv] = s;
  __syncthreads();
  if (t == 0){
    int run = 0;
    #pragma unroll
    for (int i = 0; i < 16; ++i){ int c = w_s[i]; w_s[i] = run; run += c; }
    bsum[blockIdx.x] = run;
  }
  __syncthreads();
  if (g < NN) loc[g] = s - v + w_s[wv];   // exclusive within block
}

__global__ __launch_bounds__(128) void k_scan2(const int* __restrict__ bsum,
                                               int* __restrict__ bscan){
  __shared__ int w0_s;
  int t = threadIdx.x, lane = t & 63, wv = t >> 6;
  int v = (t < 98) ? bsum[t] : 0;
  int s = v;
  #pragma unroll
  for (int o = 1; o < 64; o <<= 1){
    int u = __shfl_up(s, o, 64);
    if (lane >= o) s += u;
  }
  if (wv == 0 && lane == 63) w0_s = s;
  __syncthreads();
  if (wv == 1) s += w0_s;
  if (t < 98) bscan[t] = s - v;           // exclusive
}

__global__ __launch_bounds__(1024) void k_scan3(const int* __restrict__ loc,
                                                const int* __restrict__ bscan,
                                                int* __restrict__ cur){
  int g = blockIdx.x * 1024 + threadIdx.x;
  if (g < NN) cur[g] = loc[g] + bscan[blockIdx.x];
}

__global__ __launch_bounds__(256) void k_scatter(const int* __restrict__ ei,
    const float* __restrict__ eattr, int* __restrict__ cur,
    int* __restrict__ srcs, int* __restrict__ dsts, float* __restrict__ attrs){
  int e = blockIdx.x * 256 + threadIdx.x;
  if (e >= NE_TOT) return;
  int d = ei[NE_TOT + e];
  int p = atomicAdd(&cur[d], 1);
  srcs[p] = ei[e];
  dsts[p] = d;
  attrs[p] = eattr[e];
}

// ------------- prep GRU weights -> bf16 MFMA-B layout -------------
#define GW_LPL 102400
#define GW_O2  67584
#define GW_O3  84992
__global__ __launch_bounds__(256) void k_gprep(const float* __restrict__ wih,
                                               const float* __restrict__ whh,
                                               unsigned short* __restrict__ gw){
  int idx = blockIdx.x * 256 + threadIdx.x;
  if (idx >= 2 * 3 * 384 * 128) return;
  int which = (idx >= 3 * 384 * 128);
  int i = which ? idx - 3 * 384 * 128 : idx;
  int l = i / 49152;
  int r = i - l * 49152;
  int j = r >> 7, k = r & 127;
  float v = which ? whh[i] : wih[i];
  size_t o;
  if (!which){
    o = (j < 256) ? ((size_t)l * GW_LPL + (size_t)j * 264 + k)
                  : ((size_t)l * GW_LPL + GW_O2 + (size_t)(j - 256) * 136 + k);
  } else {
    o = (j < 256) ? ((size_t)l * GW_LPL + (size_t)j * 264 + 128 + k)
                  : ((size_t)l * GW_LPL + GW_O3 + (size_t)(j - 256) * 136 + k);
  }
  gw[o] = f2bf(v);
}

// ------------- prep message W1 -> node-GEMM layout [3][512 j][136 k] -------------
#define W1N_LS (512 * 136)
__global__ __launch_bounds__(256) void k_mprep(const float* __restrict__ w1,
                                               unsigned short* __restrict__ w1n){
  int idx = blockIdx.x * 256 + threadIdx.x;
  if (idx >= 3 * 512 * 128) return;
  int l = idx / (512 * 128);
  int r = idx - l * (512 * 128);
  int j = r >> 7, k = r & 127;
  const float* wl = w1 + (size_t)l * 257 * 256;
  float v = (j < 256) ? wl[k * 256 + j] : wl[(128 + k) * 256 + (j - 256)];
  w1n[(size_t)l * W1N_LS + j * 136 + k] = f2bf(v);
}

// ------------- prep message W2 -> [3][128 col][264 k] -------------
#define W2T_LS (128 * 264)
__global__ __launch_bounds__(256) void k_w2prep(const float* __restrict__ w2,
                                                unsigned short* __restrict__ w2T){
  int idx = blockIdx.x * 256 + threadIdx.x;
  if (idx >= 3 * 128 * 256) return;
  int l = idx >> 15;
  int r = idx & 32767;
  int c = r >> 8, k = r & 255;
  w2T[(size_t)l * W2T_LS + c * 264 + k] = f2bf(w2[(size_t)l * 256 * 128 + k * 128 + c]);
}

// ---------------- encoder: xbf = LN(relu(af @ enc_w + b)) ----------------
__global__ __launch_bounds__(256) void k_enc(const float* __restrict__ af,
    const float* __restrict__ w, const float* __restrict__ b,
    const float* __restrict__ lg, const float* __restrict__ lb,
    unsigned short* __restrict__ xbf){
  int wv = threadIdx.x >> 6, lane = threadIdx.x & 63;
  int n = blockIdx.x * 4 + wv;
  float4 a = *reinterpret_cast<const float4*>(af + (size_t)n * 4);
  int c0 = lane, c1 = lane + 64;
  float v0 = fmaf(a.x, w[c0], fmaf(a.y, w[128 + c0], fmaf(a.z, w[256 + c0], fmaf(a.w, w[384 + c0], b[c0]))));
  float v1 = fmaf(a.x, w[c1], fmaf(a.y, w[128 + c1], fmaf(a.z, w[256 + c1], fmaf(a.w, w[384 + c1], b[c1]))));
  v0 = fmaxf(v0, 0.f); v1 = fmaxf(v1, 0.f);
  float m = wave_sum64(v0 + v1) * (1.f / 128.f);
  float d0 = v0 - m, d1 = v1 - m;
  float var = wave_sum64(d0 * d0 + d1 * d1) * (1.f / 128.f);
  float rstd = rsqrtf(var + LN_EPS);
  xbf[(size_t)n * HD + c0] = f2bf(d0 * rstd * lg[c0] + lb[c0]);
  xbf[(size_t)n * HD + c1] = f2bf(d1 * rstd * lg[c1] + lb[c1]);
}

// ---------------- node GEMM: gsd[n][512] = [x@w1_top | x@w1_mid + b1] ----------------
// 2 col-half blocks (cg = blockIdx&1): block = 64 nodes x 256 cols,
// wave = 32 nodes x 128 cols, acc[2][8] = 64 VGPR -> 3+ waves/SIMD occupancy.
// cg==0 blocks also init aggr rows to indeg[n]*b2[c].
__global__ __launch_bounds__(256, 3) void k_ngemm(const unsigned short* __restrict__ xbf,
    const unsigned short* __restrict__ w1n, const float* __restrict__ b1,
    unsigned short* __restrict__ gsd, float* __restrict__ aggr,
    const int* __restrict__ cnt, const float* __restrict__ b2){
  int tid = threadIdx.x, lane = tid & 63, wv = tid >> 6;
  int r16 = lane & 15, kg = lane >> 4;
  int nb = blockIdx.x >> 1, cg = blockIdx.x & 1;
  int rg = wv >> 1, sg = wv & 1;
  // aggr init: aggr[n][c] = indeg[n] * b2[c]  (cg==0 blocks only)
  if (cg == 0){
    int nrow = NN - nb * 64; if (nrow > 64) nrow = 64;
    for (int i = tid; i < nrow * 32; i += 256){
      int row = i >> 5, c4 = (i & 31) * 4;
      int n = nb * 64 + row;
      float cv = (float)cnt[n];
      float4 bb = *reinterpret_cast<const float4*>(b2 + c4);
      bb.x *= cv; bb.y *= cv; bb.z *= cv; bb.w *= cv;
      *reinterpret_cast<float4*>(aggr + (size_t)n * HD + c4) = bb;
    }
  }
  int n0 = nb * 64 + rg * 32 + r16;
  int n1 = n0 + 16;
  int nc0 = (n0 < NN) ? n0 : NN - 1;
  int nc1 = (n1 < NN) ? n1 : NN - 1;
  short8 bfr[2][4];
  #pragma unroll
  for (int k0 = 0; k0 < 4; ++k0){
    bfr[0][k0] = *reinterpret_cast<const short8*>(xbf + (size_t)nc0 * HD + k0 * 32 + kg * 8);
    bfr[1][k0] = *reinterpret_cast<const short8*>(xbf + (size_t)nc1 * HD + k0 * 32 + kg * 8);
  }
  f32x4 acc[2][8];
  #pragma unroll
  for (int nt = 0; nt < 2; ++nt)
    #pragma unroll
    for (int it = 0; it < 8; ++it) acc[nt][it] = (f32x4){0.f, 0.f, 0.f, 0.f};
  #pragma unroll
  for (int it = 0; it < 8; ++it){
    const unsigned short* ap = w1n + (size_t)(cg * 256 + sg * 128 + it * 16 + r16) * 136 + kg * 8;
    #pragma unroll
    for (int k0 = 0; k0 < 4; ++k0){
      short8 af = *reinterpret_cast<const short8*>(ap + k0 * 32);
      acc[0][it] = __builtin_amdgcn_mfma_f32_16x16x32_bf16(af, bfr[0][k0], acc[0][it], 0, 0, 0);
      acc[1][it] = __builtin_amdgcn_mfma_f32_16x16x32_bf16(af, bfr[1][k0], acc[1][it], 0, 0, 0);
    }
  }
  #pragma unroll
  for (int nt = 0; nt < 2; ++nt){
    int n = nb * 64 + rg * 32 + nt * 16 + r16;
    if (n < NN){
      #pragma unroll
      for (int it = 0; it < 8; ++it){
        int co = sg * 128 + it * 16 + kg * 4;     // col within this cg's 256
        float v0 = acc[nt][it][0], v1 = acc[nt][it][1], v2 = acc[nt][it][2], v3 = acc[nt][it][3];
        if (cg){            // gd half: + b1
          v0 += b1[co]; v1 += b1[co + 1]; v2 += b1[co + 2]; v3 += b1[co + 3];
        }
        uint2 hp;
        hp.x = pack_bf16x2(v0, v1);
        hp.y = pack_bf16x2(v2, v3);
        *reinterpret_cast<uint2*>(gsd + (size_t)n * 512 + cg * 256 + co) = hp;
      }
    }
  }
}

// ---------------- message kernel: gather+relu -> GEMM2 -> segmented reduce ----------------
// EBM=64, LDS h_s, 4-rt-tile GEMM2 for 4x B-reuse; phase-1 pair-unpack + cvt_pk pack;
// b2 bias folded into aggr init (k_ngemm).
#define EBM 64
__global__ __launch_bounds__(256, 4) void k_msg(const unsigned short* __restrict__ gsd,
    const int* __restrict__ srcs, const int* __restrict__ dsts,
    const float* __restrict__ attrs, const float* __restrict__ w1attr,
    const unsigned short* __restrict__ w2T,
    float* __restrict__ aggr){
  __shared__ __align__(16) unsigned char smem[33280];   // h_s (32KB) / scratch f32 (33.3KB)
  unsigned short* h_s = (unsigned short*)smem;
  float* scr = (float*)smem;
  __shared__ float w1a_s[256];
  __shared__ int   dst_s[EBM];
  __shared__ float attr_s[EBM];
  int tid = threadIdx.x;
  int lane = tid & 63, wv = tid >> 6;
  int r16 = lane & 15, kg = lane >> 4;
  int ebase = blockIdx.x * EBM;

  w1a_s[tid] = w1attr[tid & 255];
  if (tid < EBM){ dst_s[tid] = dsts[ebase + tid]; attr_s[tid] = attrs[ebase + tid]; }
  __syncthreads();

  // phase 1: hidden = relu(gs[src] + gd[dst] + attr*w1attr) -> h_s bf16 (swizzled)
  {
    int e = tid >> 2, q = tid & 3;
    int sn = srcs[ebase + e];
    int dn = dst_s[e];
    float at = attr_s[e];
    const uint4* gp = reinterpret_cast<const uint4*>(gsd + (size_t)sn * 512);
    const uint4* dp = reinterpret_cast<const uint4*>(gsd + (size_t)dn * 512 + 256);
    uint4 gv[8], dv[8];
    #pragma unroll
    for (int j8 = 0; j8 < 8; ++j8){
      gv[j8] = gp[j8 * 4 + q];
      dv[j8] = dp[j8 * 4 + q];
    }
    __builtin_amdgcn_sched_barrier(0);
    #pragma unroll
    for (int j8 = 0; j8 < 8; ++j8){
      int colb = j8 * 32 + q * 8;
      unsigned int hh[4];
      unsigned int ug[4] = {gv[j8].x, gv[j8].y, gv[j8].z, gv[j8].w};
      unsigned int ud[4] = {dv[j8].x, dv[j8].y, dv[j8].z, dv[j8].w};
      #pragma unroll
      for (int w = 0; w < 4; ++w){
        float glo = asfloat_u(ug[w] << 16), ghi = asfloat_u(ug[w] & 0xFFFF0000u);
        float dlo = asfloat_u(ud[w] << 16), dhi = asfloat_u(ud[w] & 0xFFFF0000u);
        float vlo = fmaxf(glo + dlo + at * w1a_s[colb + 2 * w],     0.f);
        float vhi = fmaxf(ghi + dhi + at * w1a_s[colb + 2 * w + 1], 0.f);
        hh[w] = pack_bf16x2(vlo, vhi);
      }
      int slot = colb >> 3;
      int slotw = (slot & ~7) | ((slot ^ e) & 7);
      *reinterpret_cast<uint4*>(&h_s[e * 256 + slotw * 8]) =
          make_uint4(hh[0], hh[1], hh[2], hh[3]);
    }
  }
  __syncthreads();

  // phase 2: GEMM2 [64,256] @ [256,128] (4 row-tiles x 2 col-tiles per wave: 4x B-reuse)
  f32x4 acc2[4][2];
  #pragma unroll
  for (int rt = 0; rt < 4; ++rt)
    #pragma unroll
    for (int ct = 0; ct < 2; ++ct)
      acc2[rt][ct] = (f32x4){0.f, 0.f, 0.f, 0.f};
  int cbase2 = wv * 32;
  {
    short8 a[4], bb[2];
    const unsigned short* w2b = w2T + (size_t)(cbase2 + r16) * 264 + kg * 8;
    for (int k0 = 0; k0 < 8; ++k0){
      #pragma unroll
      for (int rt = 0; rt < 4; ++rt){
        int row = rt * 16 + r16;
        int slot = k0 * 4 + kg;
        int slotw = (slot & ~7) | ((slot ^ row) & 7);
        a[rt] = *reinterpret_cast<const short8*>(&h_s[row * 256 + slotw * 8]);
      }
      #pragma unroll
      for (int ct = 0; ct < 2; ++ct)
        bb[ct] = *reinterpret_cast<const short8*>(w2b + ct * 16 * 264 + k0 * 32);
      #pragma unroll
      for (int rt = 0; rt < 4; ++rt)
        #pragma unroll
        for (int ct = 0; ct < 2; ++ct)
          acc2[rt][ct] = __builtin_amdgcn_mfma_f32_16x16x32_bf16(a[rt], bb[ct], acc2[rt][ct], 0, 0, 0);
    }
  }
  __syncthreads();   // all h_s reads done; smem becomes scratch

  // phase 3: write messages f32 to scratch (stride 130 words: conflict-free)
  #pragma unroll
  for (int ct = 0; ct < 2; ++ct){
    int col = cbase2 + ct * 16 + r16;
    #pragma unroll
    for (int rt = 0; rt < 4; ++rt){
      #pragma unroll
      for (int r = 0; r < 4; ++r){
        int row = rt * 16 + kg * 4 + r;
        scr[row * 130 + col] = acc2[rt][ct][r];
      }
    }
  }
  __syncthreads();

  // phase 4: segmented reduce over sorted dst + atomic flush (bias pre-folded into aggr)
  {
    int c = tid & 127, h = tid >> 7;
    int r0 = h * 32;
    int pd = dst_s[r0];
    float acc = scr[r0 * 130 + c];
    #pragma unroll 4
    for (int r = 1; r < 32; ++r){
      int row = r0 + r;
      float v = scr[row * 130 + c];
      int d = dst_s[row];
      if (d != pd){
        atomicAdd(&aggr[(size_t)pd * HD + c], acc);
        acc = v; pd = d;
      } else {
        acc += v;
      }
    }
    atomicAdd(&aggr[(size_t)pd * HD + c], acc);
  }
}

// ---------------- MFMA GRUCell + residual + LayerNorm (in-place on xbf) ----------------
// 4 waves = 2 row-groups x 2 col-groups; wave = 32 rows x 64 j-cols.
// launch_bounds(256,2): measured-best register policy (110us/layer; the spill-free
// (256) variant serialized B-fetches and regressed to 129us — R15 counters).
#define GRB 64
__global__ __launch_bounds__(256, 2) void k_gru(unsigned short* __restrict__ xbf,
    const float* __restrict__ aggr,
    const unsigned short* __restrict__ gw,
    const float* __restrict__ bih, const float* __restrict__ bhh,
    const float* __restrict__ lg, const float* __restrict__ lb){
  __shared__ unsigned short a_s[GRB * 256];
  __shared__ float psum[GRB][2][2];
  int tid = threadIdx.x;
  int lane = tid & 63, wv = tid >> 6;
  int r16 = lane & 15, kg = lane >> 4;
  int rg = wv >> 1, cg = wv & 1;
  int nbase = blockIdx.x * GRB;

  // gather aggr (f32->bf16, manual cast): rows 64 x k 0..127
  {
    int row = tid >> 2, qc = (tid & 3) * 32;
    int n = nbase + row; if (n >= NN) n = NN - 1;
    const float* ap = aggr + (size_t)n * HD + qc;
    #pragma unroll
    for (int j = 0; j < 8; ++j){
      float4 v = *reinterpret_cast<const float4*>(ap + j * 4);
      ushort4 h;
      h.x = f2bf_m(v.x); h.y = f2bf_m(v.y); h.z = f2bf_m(v.z); h.w = f2bf_m(v.w);
      int col = qc + j * 4;
      int slot = col >> 3;
      int slotw = (slot & ~7) | ((slot ^ row) & 7);
      *reinterpret_cast<ushort4*>(&a_s[row * 256 + slotw * 8 + (col & 7)]) = h;
    }
  }
  // gather x (bf16): rows 64 x k 128..255
  {
    int row = tid >> 2, q = tid & 3;
    int n = nbase + row; if (n >= NN) n = NN - 1;
    const unsigned short* xp = xbf + (size_t)n * HD + q * 32;
    #pragma unroll
    for (int j = 0; j < 4; ++j){
      int4 v = *reinterpret_cast<const int4*>(xp + j * 8);
      int col = 128 + q * 32 + j * 8;
      int slot = col >> 3;
      int slotw = (slot & ~7) | ((slot ^ row) & 7);
      *reinterpret_cast<int4*>(&a_s[row * 256 + slotw * 8]) = v;
    }
  }
  __syncthreads();

  // A-fragments: 2 row-tiles x 8 K-steps
  short8 a[2][8];
  #pragma unroll
  for (int rt = 0; rt < 2; ++rt){
    int arow = rg * 32 + rt * 16 + r16;
    #pragma unroll
    for (int k0 = 0; k0 < 8; ++k0){
      int slot = k0 * 4 + kg;
      int slotw = (slot & ~7) | ((slot ^ arow) & 7);
      a[rt][k0] = *reinterpret_cast<const short8*>(&a_s[arow * 256 + slotw * 8]);
    }
  }

  f32x4 accR[2][4], accZ[2][4], accI[2][4], accH[2][4];
  #pragma unroll
  for (int rt = 0; rt < 2; ++rt)
    #pragma unroll
    for (int ct = 0; ct < 4; ++ct){
      accR[rt][ct] = (f32x4){0.f, 0.f, 0.f, 0.f};
      accZ[rt][ct] = (f32x4){0.f, 0.f, 0.f, 0.f};
      accI[rt][ct] = (f32x4){0.f, 0.f, 0.f, 0.f};
      accH[rt][ct] = (f32x4){0.f, 0.f, 0.f, 0.f};
    }

  int jb = cg * 64;
  #pragma unroll
  for (int ct = 0; ct < 4; ++ct){
    const unsigned short* bpR = gw + (size_t)(jb + ct * 16 + r16) * 264 + kg * 8;
    const unsigned short* bpZ = gw + (size_t)(128 + jb + ct * 16 + r16) * 264 + kg * 8;
    #pragma unroll
    for (int k0 = 0; k0 < 8; ++k0){
      short8 bR = *reinterpret_cast<const short8*>(bpR + k0 * 32);
      accR[0][ct] = __builtin_amdgcn_mfma_f32_16x16x32_bf16(a[0][k0], bR, accR[0][ct], 0, 0, 0);
      accR[1][ct] = __builtin_amdgcn_mfma_f32_16x16x32_bf16(a[1][k0], bR, accR[1][ct], 0, 0, 0);
      short8 bZ = *reinterpret_cast<const short8*>(bpZ + k0 * 32);
      accZ[0][ct] = __builtin_amdgcn_mfma_f32_16x16x32_bf16(a[0][k0], bZ, accZ[0][ct], 0, 0, 0);
      accZ[1][ct] = __builtin_amdgcn_mfma_f32_16x16x32_bf16(a[1][k0], bZ, accZ[1][ct], 0, 0, 0);
    }
    const unsigned short* bpI = gw + GW_O2 + (size_t)(jb + ct * 16 + r16) * 136 + kg * 8;
    const unsigned short* bpH = gw + GW_O3 + (size_t)(jb + ct * 16 + r16) * 136 + kg * 8;
    #pragma unroll
    for (int k0 = 0; k0 < 4; ++k0){
      short8 bI = *reinterpret_cast<const short8*>(bpI + k0 * 32);
      accI[0][ct] = __builtin_amdgcn_mfma_f32_16x16x32_bf16(a[0][k0], bI, accI[0][ct], 0, 0, 0);
      accI[1][ct] = __builtin_amdgcn_mfma_f32_16x16x32_bf16(a[1][k0], bI, accI[1][ct], 0, 0, 0);
      short8 bH = *reinterpret_cast<const short8*>(bpH + k0 * 32);
      accH[0][ct] = __builtin_amdgcn_mfma_f32_16x16x32_bf16(a[0][k0 + 4], bH, accH[0][ct], 0, 0, 0);
      accH[1][ct] = __builtin_amdgcn_mfma_f32_16x16x32_bf16(a[1][k0 + 4], bH, accH[1][ct], 0, 0, 0);
    }
  }

  // gates + residual; pre-LN value overwrites accR (fast tanh: 2*sigma(2x)-1).
  // Residual x read from LDS a_s (cols 128..255) — no global xbf re-read.
  #pragma unroll
  for (int rt = 0; rt < 2; ++rt){
    #pragma unroll
    for (int ct = 0; ct < 4; ++ct){
      int j = jb + ct * 16 + r16;
      float br = bih[j] + bhh[j];
      float bz = bih[j + 128] + bhh[j + 128];
      float bin = bih[j + 256], bhn = bhh[j + 256];
      #pragma unroll
      for (int r = 0; r < 4; ++r){
        int row = rg * 32 + rt * 16 + kg * 4 + r;
        int col = 128 + j;
        int slot = col >> 3;
        int slotw = (slot & ~7) | ((slot ^ row) & 7);
        float xv = bf2f(a_s[row * 256 + slotw * 8 + (col & 7)]);
        float rgt = accR[rt][ct][r] + br;  rgt = 1.f / (1.f + __expf(-rgt));
        float zg  = accZ[rt][ct][r] + bz;  zg  = 1.f / (1.f + __expf(-zg));
        float na  = accI[rt][ct][r] + bin + rgt * (accH[rt][ct][r] + bhn);
        float sg  = 1.f / (1.f + __expf(-2.f * na));
        float ng  = fmaf(2.f, sg, -1.f);
        accR[rt][ct][r] = xv + (1.f - zg) * ng + zg * xv;   // pre-LN
      }
    }
  }

  // cross-wave LN: per-row partial (sum, sumsq) via 16-lane shfl -> LDS psum[row][cg]
  #pragma unroll
  for (int rt = 0; rt < 2; ++rt){
    #pragma unroll
    for (int r = 0; r < 4; ++r){
      float s = 0.f, q = 0.f;
      #pragma unroll
      for (int ct = 0; ct < 4; ++ct){ float v = accR[rt][ct][r]; s += v; q += v * v; }
      #pragma unroll
      for (int o = 1; o <= 8; o <<= 1){ s += __shfl_xor(s, o, 64); q += __shfl_xor(q, o, 64); }
      if (r16 == 0){
        int l = rg * 32 + rt * 16 + kg * 4 + r;
        psum[l][cg][0] = s;
        psum[l][cg][1] = q;
      }
    }
  }
  __syncthreads();

  #pragma unroll
  for (int rt = 0; rt < 2; ++rt){
    #pragma unroll
    for (int r = 0; r < 4; ++r){
      int l = rg * 32 + rt * 16 + kg * 4 + r;
      float S = psum[l][0][0] + psum[l][1][0];
      float Q = psum[l][0][1] + psum[l][1][1];
      float m = S * (1.f / 128.f);
      float var = Q * (1.f / 128.f) - m * m;
      float rstd = rsqrtf(fmaxf(var, 0.f) + LN_EPS);
      int n = nbase + rg * 32 + rt * 16 + kg * 4 + r;
      if (n < NN){
        #pragma unroll
        for (int ct = 0; ct < 4; ++ct){
          int j = jb + ct * 16 + r16;
          xbf[(size_t)n * HD + j] = f2bf_m((accR[rt][ct][r] - m) * rstd * lg[j] + lb[j]);
        }
      }
    }
  }
}

// ---------------- pooling + readout MLP ----------------
__device__ __forceinline__ int lowerb(const int* __restrict__ a, int v){
  int lo = 0, hi = NN;
  while (lo < hi){ int mid = (lo + hi) >> 1; if (a[mid] < v) lo = mid + 1; else hi = mid; }
  return lo;
}

__global__ __launch_bounds__(128) void k_pool(const unsigned short* __restrict__ xbf,
    const int* __restrict__ batch,
    const float* __restrict__ w1, const float* __restrict__ b1,
    const float* __restrict__ w2, const float* __restrict__ b2,
    const float* __restrict__ w3, const float* __restrict__ b3,
    float* __restrict__ out){
  __shared__ float g_s[256];
  __shared__ float h1_s[128];
  __shared__ float h2_s[64];
  int g = blockIdx.x, tid = threadIdx.x;
  int s = lowerb(batch, g), t = lowerb(batch, g + 1);
  float sum = 0.f, mx = -INFINITY;
  for (int n = s; n < t; ++n){
    float v = bf2f(xbf[(size_t)n * HD + tid]);
    sum += v; mx = fmaxf(mx, v);
  }
  int cnt = t - s;
  g_s[tid]       = sum / fmaxf((float)cnt, 1.f);
  g_s[tid + 128] = (cnt > 0) ? mx : -INFINITY;
  __syncthreads();
  float a1 = b1[tid];
  for (int k = 0; k < 256; ++k) a1 = fmaf(g_s[k], w1[k * 128 + tid], a1);
  h1_s[tid] = fmaxf(a1, 0.f);
  __syncthreads();
  if (tid < 64){
    float a2 = b2[tid];
    for (int k = 0; k < 128; ++k) a2 = fmaf(h1_s[k], w2[k * 64 + tid], a2);
    h2_s[tid] = fmaxf(a2, 0.f);
  }
  __syncthreads();
  if (tid < 113){
    float a3 = b3[tid];
    for (int k = 0; k < 64; ++k) a3 = fmaf(h2_s[k], w3[k * 113 + tid], a3);
    out[(size_t)g * 113 + tid] = a3;
  }
}

// ---------------- launcher ----------------
extern "C" void kernel_launch(void* const* d_in, const int* in_sizes, int n_in,
                              void* d_out, int out_size, void* d_ws, size_t ws_size,
                              hipStream_t stream){
  (void)in_sizes; (void)n_in; (void)out_size; (void)ws_size;
  const float* af     = (const float*)d_in[0];
  const int*   ei     = (const int*)  d_in[1];
  const float* eattr  = (const float*)d_in[2];
  const int*   batch  = (const int*)  d_in[3];
  const float* enc_w  = (const float*)d_in[4];
  const float* enc_b  = (const float*)d_in[5];
  const float* enc_lg = (const float*)d_in[6];
  const float* enc_lb = (const float*)d_in[7];
  const float* mw1    = (const float*)d_in[8];
  const float* mb1    = (const float*)d_in[9];
  const float* mw2    = (const float*)d_in[10];
  const float* mb2    = (const float*)d_in[11];
  const float* gwih   = (const float*)d_in[12];
  const float* gwhh   = (const float*)d_in[13];
  const float* gbih   = (const float*)d_in[14];
  const float* gbhh   = (const float*)d_in[15];
  const float* lng    = (const float*)d_in[16];
  const float* lnb    = (const float*)d_in[17];
  const float* rw1    = (const float*)d_in[18];
  const float* rb1    = (const float*)d_in[19];
  const float* rw2    = (const float*)d_in[20];
  const float* rb2    = (const float*)d_in[21];
  const float* rw3    = (const float*)d_in[22];
  const float* rb3    = (const float*)d_in[23];
  float* out = (float*)d_out;
  char* ws = (char*)d_ws;

  size_t off = 0;
  auto carve = [&](size_t bytes)->char*{
    char* p = ws + off;
    off = (off + bytes + 255) & ~(size_t)255;
    return p;
  };
  unsigned short* xbf  = (unsigned short*)carve((size_t)NN * HD * 2);       // 25.6 MB
  float*          aggr = (float*)         carve((size_t)NN * HD * 4);       // 51.2 MB
  unsigned short* gsd  = (unsigned short*)carve((size_t)NN * 512 * 2);      // 102.4 MB
  unsigned short* gw   = (unsigned short*)carve((size_t)3 * GW_LPL * 2);
  unsigned short* w1n  = (unsigned short*)carve((size_t)3 * W1N_LS * 2);
  unsigned short* w2T  = (unsigned short*)carve((size_t)3 * W2T_LS * 2);
  int*   cnt   = (int*)  carve((size_t)NN * 4);
  int*   cur   = (int*)  carve((size_t)NN * 4);
  int*   loc   = (int*)  carve((size_t)NN * 4);
  int*   bsum  = (int*)  carve((size_t)128 * 4);
  int*   bscan = (int*)  carve((size_t)128 * 4);
  int*   srcs  = (int*)  carve((size_t)NE_TOT * 4);
  int*   dsts  = (int*)  carve((size_t)NE_TOT * 4);
  float* attrs = (float*)carve((size_t)NE_TOT * 4);

  // one-time: CSR sort + weight preps + encoder
  k_zero4<<<(NN / 4 + 255) / 256, 256, 0, stream>>>((float4*)cnt, NN / 4);
  k_hist<<<(NE_TOT + 255) / 256, 256, 0, stream>>>(ei, cnt);
  k_scan1<<<98, 1024, 0, stream>>>(cnt, loc, bsum);
  k_scan2<<<1, 128, 0, stream>>>(bsum, bscan);
  k_scan3<<<98, 1024, 0, stream>>>(loc, bscan, cur);
  k_scatter<<<(NE_TOT + 255) / 256, 256, 0, stream>>>(ei, eattr, cur, srcs, dsts, attrs);
  k_gprep<<<1152, 256, 0, stream>>>(gwih, gwhh, gw);
  k_mprep<<<768, 256, 0, stream>>>(mw1, w1n);
  k_w2prep<<<384, 256, 0, stream>>>(mw2, w2T);
  k_enc<<<NN / 4, 256, 0, stream>>>(af, enc_w, enc_b, enc_lg, enc_lb, xbf);

  for (int l = 0; l < NL; ++l){
    k_ngemm<<<2 * ((NN + 63) / 64), 256, 0, stream>>>(xbf,
        w1n + (size_t)l * W1N_LS, mb1 + (size_t)l * 256, gsd, aggr,
        cnt, mb2 + (size_t)l * 128);
    k_msg<<<NE_TOT / EBM, 256, 0, stream>>>(gsd, srcs, dsts, attrs,
        mw1 + (size_t)l * 257 * 256 + 256 * 256,
        w2T + (size_t)l * W2T_LS, aggr);
    k_gru<<<(NN + GRB - 1) / GRB, 256, 0, stream>>>(xbf, aggr,
        gw + (size_t)l * GW_LPL,
        gbih + (size_t)l * 384, gbhh + (size_t)l * 384,
        lng + (size_t)l * HD, lnb + (size_t)l * HD);
  }
  k_pool<<<NG, 128, 0, stream>>>(xbf, batch, rw1, rb1, rw2, rb2, rw3, rb3, out);
}